// Round 1
// baseline (1319.458 us; speedup 1.0000x reference)
//
#include <hip/hip_runtime.h>

#define BB 2
#define NN 4096
#define MM 12288
#define HH 8
#define CC 256

typedef float f32x4 __attribute__((ext_vector_type(4)));
typedef __bf16 bf16x8 __attribute__((ext_vector_type(8)));

__device__ __forceinline__ unsigned short f2bf(float f) {
    union { float f; unsigned u; } v; v.f = f;
    unsigned r = (v.u + 0x7FFFu + ((v.u >> 16) & 1u)) >> 16;
    return (unsigned short)r;
}
__device__ __forceinline__ unsigned pk2(float a, float b) {
    return (unsigned)f2bf(a) | ((unsigned)f2bf(b) << 16);
}

// ---------------------------------------------------------------------------
// proj: out[r,e] = sum_d X[r,d] * W[e,d]   (X: (R,256) f32, W: (256,256) f32)
// mode 0: f32 out with per-32-col (per-head) LayerNorm
// mode 1: bf16 transposed out: outT[(b*256+c)*Nb + n], b = r/Nb, n = r%Nb
// ---------------------------------------------------------------------------
__global__ __launch_bounds__(256) void proj_kernel(
    const float* __restrict__ X, const float* __restrict__ W,
    float* __restrict__ outF, unsigned short* __restrict__ outT,
    int Nb, int mode)
{
    __shared__ unsigned short Al[64][264];
    __shared__ unsigned short Wl[32][264];
    const int t = threadIdx.x;
    const long rowbase = (long)blockIdx.x * 64;
    const int lane = t & 63, w = t >> 6, q = lane >> 4, l15 = lane & 15;

    // stage A: 64 rows x 256 f32 -> bf16
    {
        const float* Xp = X + rowbase * CC;
        #pragma unroll
        for (int i = 0; i < 16; ++i) {
            int f = t + i * 256;
            int row = f >> 6, k4 = (f & 63) << 2;
            f32x4 v = *(const f32x4*)(Xp + row * CC + k4);
            *(uint2*)(&Al[row][k4]) = make_uint2(pk2(v[0], v[1]), pk2(v[2], v[3]));
        }
    }

    const int wrow = w * 16;
    for (int ct = 0; ct < 8; ++ct) {
        __syncthreads();
        #pragma unroll
        for (int i = 0; i < 8; ++i) {
            int f = t + i * 256;
            int row = f >> 6, k4 = (f & 63) << 2;
            f32x4 v = *(const f32x4*)(W + (ct * 32 + row) * CC + k4);
            *(uint2*)(&Wl[row][k4]) = make_uint2(pk2(v[0], v[1]), pk2(v[2], v[3]));
        }
        __syncthreads();
        f32x4 acc0 = {0.f, 0.f, 0.f, 0.f}, acc1 = {0.f, 0.f, 0.f, 0.f};
        #pragma unroll
        for (int kk = 0; kk < 8; ++kk) {
            bf16x8 af = *(const bf16x8*)(&Al[wrow + l15][kk * 32 + q * 8]);
            bf16x8 b0 = *(const bf16x8*)(&Wl[l15][kk * 32 + q * 8]);
            bf16x8 b1 = *(const bf16x8*)(&Wl[16 + l15][kk * 32 + q * 8]);
            acc0 = __builtin_amdgcn_mfma_f32_16x16x32_bf16(af, b0, acc0, 0, 0, 0);
            acc1 = __builtin_amdgcn_mfma_f32_16x16x32_bf16(af, b1, acc1, 0, 0, 0);
        }
        if (mode == 0) {
            #pragma unroll
            for (int r = 0; r < 4; ++r) {
                float s = acc0[r] + acc1[r];
                s += __shfl_xor(s, 1); s += __shfl_xor(s, 2);
                s += __shfl_xor(s, 4); s += __shfl_xor(s, 8);
                float mu = s * (1.0f / 32.0f);
                float a0 = acc0[r] - mu, a1 = acc1[r] - mu;
                float sq = a0 * a0 + a1 * a1;
                sq += __shfl_xor(sq, 1); sq += __shfl_xor(sq, 2);
                sq += __shfl_xor(sq, 4); sq += __shfl_xor(sq, 8);
                float rs = rsqrtf(sq * (1.0f / 32.0f) + 1e-5f);
                long row = rowbase + wrow + q * 4 + r;
                outF[row * CC + ct * 32 + l15] = a0 * rs;
                outF[row * CC + ct * 32 + 16 + l15] = a1 * rs;
            }
        } else {
            long row = rowbase + wrow + q * 4;   // 4 consecutive rows, same batch
            int b = (row >= Nb) ? 1 : 0;
            long n = row - (long)b * Nb;
            int c0 = ct * 32 + l15;
            unsigned short* p0 = outT + ((long)(b * CC + c0)) * Nb + n;
            *(uint2*)p0 = make_uint2(pk2(acc0[0], acc0[1]), pk2(acc0[2], acc0[3]));
            unsigned short* p1 = outT + ((long)(b * CC + c0 + 16)) * Nb + n;
            *(uint2*)p1 = make_uint2(pk2(acc1[0], acc1[1]), pk2(acc1[2], acc1[3]));
        }
    }
}

// ---------------------------------------------------------------------------
// attention weights: one thread per (b, r, h)
// w[b,r,h,k] = softmax_k( Q[b,r,h*32:]·K[b,idx[r,k],h*32:] / sqrt(32) )
// ---------------------------------------------------------------------------
__global__ __launch_bounds__(256) void attnw_kernel(
    const float* __restrict__ Q, const float* __restrict__ K,
    const int* __restrict__ idx, float* __restrict__ wout, int R)
{
    long tid = (long)blockIdx.x * 256 + threadIdx.x;
    int h = (int)(tid & 7);
    long br = tid >> 3;                 // b*R + r
    int b = (br >= R) ? 1 : 0;
    long r = br - (long)b * R;
    const float* qp = Q + br * CC + h * 32;
    f32x4 qv[8];
    #pragma unroll
    for (int i = 0; i < 8; ++i) qv[i] = *(const f32x4*)(qp + 4 * i);
    const int* ip = idx + r * 16;
    float sc[16];
    #pragma unroll
    for (int k = 0; k < 16; ++k) {
        const float* kp = K + ((long)b * R + ip[k]) * CC + h * 32;
        float d = 0.f;
        #pragma unroll
        for (int i = 0; i < 8; ++i) {
            f32x4 kv = *(const f32x4*)(kp + 4 * i);
            d += qv[i][0] * kv[0] + qv[i][1] * kv[1] + qv[i][2] * kv[2] + qv[i][3] * kv[3];
        }
        sc[k] = d * 0.17677669529663687f;   // 1/sqrt(32)
    }
    float mx = sc[0];
    #pragma unroll
    for (int k = 1; k < 16; ++k) mx = fmaxf(mx, sc[k]);
    float sum = 0.f;
    #pragma unroll
    for (int k = 0; k < 16; ++k) { sc[k] = __expf(sc[k] - mx); sum += sc[k]; }
    float inv = 1.0f / sum;
    float* op = wout + tid * 16;
    #pragma unroll
    for (int i = 0; i < 4; ++i) {
        f32x4 v = { sc[4*i] * inv, sc[4*i+1] * inv, sc[4*i+2] * inv, sc[4*i+3] * inv };
        *(f32x4*)(op + 4 * i) = v;
    }
}

// ---------------------------------------------------------------------------
// gemm1: x1[b,m,c] = sum_n d0[b,m,n] * vVt[b,c,n]    (f32 A converted to bf16)
// grid (M/128, C/64, B), 256 threads, wave tile 64x32, BK=64
// ---------------------------------------------------------------------------
__global__ __launch_bounds__(256) void gemm1_kernel(
    const float* __restrict__ d0, const unsigned short* __restrict__ vVt,
    float* __restrict__ x1)
{
    __shared__ unsigned short Alds[128][72];
    __shared__ unsigned short Blds[64][72];
    const int t = threadIdx.x;
    const int b = blockIdx.z;
    const long m0 = (long)blockIdx.x * 128;
    const int c0 = blockIdx.y * 64;
    const float* Ap = d0 + (long)b * MM * NN + m0 * NN;
    const unsigned short* Bp = vVt + ((long)b * CC + c0) * NN;
    const int lane = t & 63, w = t >> 6, q = lane >> 4, l15 = lane & 15;
    const int wr = (w >> 1) * 64, wc = (w & 1) * 32;
    f32x4 acc[4][2];
    #pragma unroll
    for (int i = 0; i < 4; ++i)
        #pragma unroll
        for (int j = 0; j < 2; ++j) acc[i][j] = {0.f, 0.f, 0.f, 0.f};
    const int arow = t >> 4, ak4 = (t & 15) << 2;
    const int brow = t >> 3, bk8 = (t & 7) << 3;
    for (int k0 = 0; k0 < NN; k0 += 64) {
        #pragma unroll
        for (int i = 0; i < 8; ++i) {
            int row = arow + i * 16;
            f32x4 v = *(const f32x4*)(Ap + (long)row * NN + k0 + ak4);
            *(uint2*)(&Alds[row][ak4]) = make_uint2(pk2(v[0], v[1]), pk2(v[2], v[3]));
        }
        #pragma unroll
        for (int i = 0; i < 2; ++i) {
            int row = brow + i * 32;
            *(uint4*)(&Blds[row][bk8]) = *(const uint4*)(Bp + (long)row * NN + k0 + bk8);
        }
        __syncthreads();
        #pragma unroll
        for (int kh = 0; kh < 2; ++kh) {
            bf16x8 a[4], bb[2];
            #pragma unroll
            for (int i = 0; i < 4; ++i)
                a[i] = *(const bf16x8*)(&Alds[wr + i * 16 + l15][kh * 32 + q * 8]);
            #pragma unroll
            for (int j = 0; j < 2; ++j)
                bb[j] = *(const bf16x8*)(&Blds[wc + j * 16 + l15][kh * 32 + q * 8]);
            #pragma unroll
            for (int i = 0; i < 4; ++i)
                #pragma unroll
                for (int j = 0; j < 2; ++j)
                    acc[i][j] = __builtin_amdgcn_mfma_f32_16x16x32_bf16(a[i], bb[j], acc[i][j], 0, 0, 0);
        }
        __syncthreads();
    }
    #pragma unroll
    for (int i = 0; i < 4; ++i)
        #pragma unroll
        for (int j = 0; j < 2; ++j)
            #pragma unroll
            for (int r = 0; r < 4; ++r) {
                long m = m0 + wr + i * 16 + q * 4 + r;
                int c = c0 + wc + j * 16 + l15;
                x1[((long)b * MM + m) * CC + c] = acc[i][j][r];
            }
}

// ---------------------------------------------------------------------------
// gather_e: x2t[b,c,m] = bf16( sum_k ae[b,m,h(c),k] * x1[b, eidx[m,k], c] )
// grid (M/64, B)
// ---------------------------------------------------------------------------
__global__ __launch_bounds__(256) void gather_e_kernel(
    const float* __restrict__ x1, const float* __restrict__ ae,
    const int* __restrict__ eidx, unsigned short* __restrict__ x2t)
{
    __shared__ unsigned short T[256][72];
    const int t = threadIdx.x;
    const int b = blockIdx.y;
    const int m0 = blockIdx.x * 64;
    const int h = t >> 5;
    const float* x1b = x1 + (long)b * MM * CC;
    for (int ml = 0; ml < 64; ++ml) {
        int m = m0 + ml;
        const int* ip = eidx + (long)m * 16;
        const float* wp = ae + ((long)b * MM + m) * 128 + h * 16;
        float acc = 0.f;
        #pragma unroll
        for (int k = 0; k < 16; ++k)
            acc += wp[k] * x1b[(long)ip[k] * CC + t];
        T[t][ml] = f2bf(acc);
    }
    __syncthreads();
    unsigned short* dst = x2t + ((long)b * CC + t) * MM + m0;
    #pragma unroll
    for (int i = 0; i < 8; ++i)
        *(uint4*)(dst + i * 8) = *(const uint4*)(&T[t][i * 8]);
}

// ---------------------------------------------------------------------------
// gemm2: x3[s,b,n,c] = sum_{m in half s} d0[b,m,n] * x2t[b,c,m]
// grid (N/128, C/64, B*2), BK=32, in-register 4x4 transpose of d0
// ---------------------------------------------------------------------------
__global__ __launch_bounds__(256) void gemm2_kernel(
    const float* __restrict__ d0, const unsigned short* __restrict__ x2t,
    float* __restrict__ x3)
{
    __shared__ unsigned short Alds[128][40];
    __shared__ unsigned short Blds[64][40];
    const int t = threadIdx.x;
    const int b = blockIdx.z >> 1, s = blockIdx.z & 1;
    const long n0 = (long)blockIdx.x * 128;
    const int c0 = blockIdx.y * 64;
    const float* Ap = d0 + (long)b * MM * NN + n0;
    const unsigned short* Bp = x2t + ((long)b * CC + c0) * MM;
    const int lane = t & 63, w = t >> 6, q = lane >> 4, l15 = lane & 15;
    const int wr = (w >> 1) * 64, wc = (w & 1) * 32;
    f32x4 acc[4][2];
    #pragma unroll
    for (int i = 0; i < 4; ++i)
        #pragma unroll
        for (int j = 0; j < 2; ++j) acc[i][j] = {0.f, 0.f, 0.f, 0.f};
    const int kq = t & 7, nq = t >> 3;
    const int bc = t >> 2, bk8 = (t & 3) << 3;
    const int kbeg = s * (MM / 2), kend = kbeg + MM / 2;
    for (int k0 = kbeg; k0 < kend; k0 += 32) {
        f32x4 v[4];
        #pragma unroll
        for (int i = 0; i < 4; ++i)
            v[i] = *(const f32x4*)(Ap + (long)(k0 + 4 * kq + i) * NN + 4 * nq);
        #pragma unroll
        for (int j = 0; j < 4; ++j)
            *(uint2*)(&Alds[4 * nq + j][4 * kq]) =
                make_uint2(pk2(v[0][j], v[1][j]), pk2(v[2][j], v[3][j]));
        *(uint4*)(&Blds[bc][bk8]) = *(const uint4*)(Bp + (long)bc * MM + k0 + bk8);
        __syncthreads();
        bf16x8 a[4], bb[2];
        #pragma unroll
        for (int i = 0; i < 4; ++i)
            a[i] = *(const bf16x8*)(&Alds[wr + i * 16 + l15][q * 8]);
        #pragma unroll
        for (int j = 0; j < 2; ++j)
            bb[j] = *(const bf16x8*)(&Blds[wc + j * 16 + l15][q * 8]);
        #pragma unroll
        for (int i = 0; i < 4; ++i)
            #pragma unroll
            for (int j = 0; j < 2; ++j)
                acc[i][j] = __builtin_amdgcn_mfma_f32_16x16x32_bf16(a[i], bb[j], acc[i][j], 0, 0, 0);
        __syncthreads();
    }
    #pragma unroll
    for (int i = 0; i < 4; ++i)
        #pragma unroll
        for (int j = 0; j < 2; ++j)
            #pragma unroll
            for (int r = 0; r < 4; ++r) {
                long n = n0 + wr + i * 16 + q * 4 + r;
                int c = c0 + wc + j * 16 + l15;
                x3[(((long)s * BB + b) * NN + n) * CC + c] = acc[i][j][r];
            }
}

// ---------------------------------------------------------------------------
// gather_v: out[b,n,c] = sum_k av[b,n,h(c),k] * (x3[0,b,vidx[n,k],c] + x3[1,...])
// grid (N, B)
// ---------------------------------------------------------------------------
__global__ __launch_bounds__(256) void gather_v_kernel(
    const float* __restrict__ x3, const float* __restrict__ av,
    const int* __restrict__ vidx, float* __restrict__ out)
{
    const int t = threadIdx.x;
    const int b = blockIdx.y;
    const int n = blockIdx.x;
    const int h = t >> 5;
    const float* xa = x3 + (long)b * NN * CC;
    const float* xb = x3 + ((long)BB + b) * NN * CC;
    const int* ip = vidx + (long)n * 16;
    const float* wp = av + ((long)b * NN + n) * 128 + h * 16;
    float acc = 0.f;
    #pragma unroll
    for (int k = 0; k < 16; ++k) {
        long j = ip[k];
        acc += wp[k] * (xa[j * CC + t] + xb[j * CC + t]);
    }
    out[((long)b * NN + n) * CC + t] = acc;
}

// ---------------------------------------------------------------------------
extern "C" void kernel_launch(void* const* d_in, const int* in_sizes, int n_in,
                              void* d_out, int out_size, void* d_ws, size_t ws_size,
                              hipStream_t stream)
{
    const float* x_v = (const float*)d_in[0];
    const float* x_e = (const float*)d_in[1];
    const float* d0  = (const float*)d_in[2];
    const float* WvQ = (const float*)d_in[3];
    const float* WvK = (const float*)d_in[4];
    const float* WvV = (const float*)d_in[5];
    const float* WeQ = (const float*)d_in[6];
    const float* WeK = (const float*)d_in[7];
    const int* vidx  = (const int*)d_in[8];
    const int* eidx  = (const int*)d_in[9];

    char* ws = (char*)d_ws;
    size_t off = 0;
    auto alloc = [&](size_t bytes) -> void* {
        void* p = ws + off;
        off += (bytes + 255) & ~(size_t)255;
        return p;
    };
    float* vQ  = (float*)alloc((size_t)BB * NN * CC * 4);
    float* vK  = (float*)alloc((size_t)BB * NN * CC * 4);
    unsigned short* vVt = (unsigned short*)alloc((size_t)BB * CC * NN * 2);
    float* eQ  = (float*)alloc((size_t)BB * MM * CC * 4);
    float* eK  = (float*)alloc((size_t)BB * MM * CC * 4);
    float* ae  = (float*)alloc((size_t)BB * MM * HH * 16 * 4);
    float* av  = (float*)alloc((size_t)BB * NN * HH * 16 * 4);
    float* x1  = (float*)alloc((size_t)BB * MM * CC * 4);
    unsigned short* x2t = (unsigned short*)alloc((size_t)BB * CC * MM * 2);
    float* x3  = (float*)alloc((size_t)2 * BB * NN * CC * 4);
    if (off > ws_size) return;   // workspace too small: fail cleanly

    proj_kernel<<<dim3((BB * NN) / 64), 256, 0, stream>>>(x_v, WvQ, vQ, nullptr, NN, 0);
    proj_kernel<<<dim3((BB * NN) / 64), 256, 0, stream>>>(x_v, WvK, vK, nullptr, NN, 0);
    proj_kernel<<<dim3((BB * NN) / 64), 256, 0, stream>>>(x_v, WvV, nullptr, vVt, NN, 1);
    proj_kernel<<<dim3((BB * MM) / 64), 256, 0, stream>>>(x_e, WeQ, eQ, nullptr, MM, 0);
    proj_kernel<<<dim3((BB * MM) / 64), 256, 0, stream>>>(x_e, WeK, eK, nullptr, MM, 0);
    attnw_kernel<<<dim3((BB * MM * HH) / 256), 256, 0, stream>>>(eQ, eK, eidx, ae, MM);
    // second sparse attention uses q = v_K, k = v_Q (note the swap in the reference)
    attnw_kernel<<<dim3((BB * NN * HH) / 256), 256, 0, stream>>>(vK, vQ, vidx, av, NN);
    gemm1_kernel<<<dim3(MM / 128, CC / 64, BB), 256, 0, stream>>>(d0, vVt, x1);
    gather_e_kernel<<<dim3(MM / 64, BB), 256, 0, stream>>>(x1, ae, eidx, x2t);
    gemm2_kernel<<<dim3(NN / 128, CC / 64, BB * 2), 256, 0, stream>>>(d0, x2t, x3);
    gather_v_kernel<<<dim3(NN, BB), 256, 0, stream>>>(x3, av, vidx, (float*)d_out);
}

// Round 2
// 1243.939 us; speedup vs baseline: 1.0607x; 1.0607x over previous
//
#include <hip/hip_runtime.h>

#define BB 2
#define NN 4096
#define MM 12288
#define HH 8
#define CC 256

typedef float f32x4 __attribute__((ext_vector_type(4)));
typedef __bf16 bf16x8 __attribute__((ext_vector_type(8)));

__device__ __forceinline__ unsigned short f2bf(float f) {
    union { float f; unsigned u; } v; v.f = f;
    unsigned r = (v.u + 0x7FFFu + ((v.u >> 16) & 1u)) >> 16;
    return (unsigned short)r;
}
__device__ __forceinline__ unsigned pk2(float a, float b) {
    return (unsigned)f2bf(a) | ((unsigned)f2bf(b) << 16);
}
__device__ __forceinline__ void gll16(const unsigned short* g, unsigned short* l) {
    __builtin_amdgcn_global_load_lds(
        (__attribute__((address_space(1))) void*)(g),
        (__attribute__((address_space(3))) void*)(l), 16, 0, 0);
}

// ---------------------------------------------------------------------------
// proj: out[r,e] = sum_d X[r,d] * W[e,d]
// mode 0: f32 out with per-32-col (per-head) LayerNorm
// mode 1: bf16 transposed out: outT[(b*256+c)*Nb + n]
// ---------------------------------------------------------------------------
__global__ __launch_bounds__(256) void proj_kernel(
    const float* __restrict__ X, const float* __restrict__ W,
    float* __restrict__ outF, unsigned short* __restrict__ outT,
    int Nb, int mode)
{
    __shared__ unsigned short Al[64][264];
    __shared__ unsigned short Wl[32][264];
    const int t = threadIdx.x;
    const long rowbase = (long)blockIdx.x * 64;
    const int lane = t & 63, w = t >> 6, q = lane >> 4, l15 = lane & 15;

    {
        const float* Xp = X + rowbase * CC;
        #pragma unroll
        for (int i = 0; i < 16; ++i) {
            int f = t + i * 256;
            int row = f >> 6, k4 = (f & 63) << 2;
            f32x4 v = *(const f32x4*)(Xp + row * CC + k4);
            *(uint2*)(&Al[row][k4]) = make_uint2(pk2(v[0], v[1]), pk2(v[2], v[3]));
        }
    }

    const int wrow = w * 16;
    for (int ct = 0; ct < 8; ++ct) {
        __syncthreads();
        #pragma unroll
        for (int i = 0; i < 8; ++i) {
            int f = t + i * 256;
            int row = f >> 6, k4 = (f & 63) << 2;
            f32x4 v = *(const f32x4*)(W + (ct * 32 + row) * CC + k4);
            *(uint2*)(&Wl[row][k4]) = make_uint2(pk2(v[0], v[1]), pk2(v[2], v[3]));
        }
        __syncthreads();
        f32x4 acc0 = {0.f, 0.f, 0.f, 0.f}, acc1 = {0.f, 0.f, 0.f, 0.f};
        #pragma unroll
        for (int kk = 0; kk < 8; ++kk) {
            bf16x8 af = *(const bf16x8*)(&Al[wrow + l15][kk * 32 + q * 8]);
            bf16x8 b0 = *(const bf16x8*)(&Wl[l15][kk * 32 + q * 8]);
            bf16x8 b1 = *(const bf16x8*)(&Wl[16 + l15][kk * 32 + q * 8]);
            acc0 = __builtin_amdgcn_mfma_f32_16x16x32_bf16(af, b0, acc0, 0, 0, 0);
            acc1 = __builtin_amdgcn_mfma_f32_16x16x32_bf16(af, b1, acc1, 0, 0, 0);
        }
        if (mode == 0) {
            #pragma unroll
            for (int r = 0; r < 4; ++r) {
                float s = acc0[r] + acc1[r];
                s += __shfl_xor(s, 1); s += __shfl_xor(s, 2);
                s += __shfl_xor(s, 4); s += __shfl_xor(s, 8);
                float mu = s * (1.0f / 32.0f);
                float a0 = acc0[r] - mu, a1 = acc1[r] - mu;
                float sq = a0 * a0 + a1 * a1;
                sq += __shfl_xor(sq, 1); sq += __shfl_xor(sq, 2);
                sq += __shfl_xor(sq, 4); sq += __shfl_xor(sq, 8);
                float rs = rsqrtf(sq * (1.0f / 32.0f) + 1e-5f);
                long row = rowbase + wrow + q * 4 + r;
                outF[row * CC + ct * 32 + l15] = a0 * rs;
                outF[row * CC + ct * 32 + 16 + l15] = a1 * rs;
            }
        } else {
            long row = rowbase + wrow + q * 4;
            int b = (row >= Nb) ? 1 : 0;
            long n = row - (long)b * Nb;
            int c0 = ct * 32 + l15;
            unsigned short* p0 = outT + ((long)(b * CC + c0)) * Nb + n;
            *(uint2*)p0 = make_uint2(pk2(acc0[0], acc0[1]), pk2(acc0[2], acc0[3]));
            unsigned short* p1 = outT + ((long)(b * CC + c0 + 16)) * Nb + n;
            *(uint2*)p1 = make_uint2(pk2(acc1[0], acc1[1]), pk2(acc1[2], acc1[3]));
        }
    }
}

// ---------------------------------------------------------------------------
// attention weights: one thread per (b, r, h)
// ---------------------------------------------------------------------------
__global__ __launch_bounds__(256) void attnw_kernel(
    const float* __restrict__ Q, const float* __restrict__ K,
    const int* __restrict__ idx, float* __restrict__ wout, int R)
{
    long tid = (long)blockIdx.x * 256 + threadIdx.x;
    int h = (int)(tid & 7);
    long br = tid >> 3;
    int b = (br >= R) ? 1 : 0;
    long r = br - (long)b * R;
    const float* qp = Q + br * CC + h * 32;
    f32x4 qv[8];
    #pragma unroll
    for (int i = 0; i < 8; ++i) qv[i] = *(const f32x4*)(qp + 4 * i);
    const int* ip = idx + r * 16;
    float sc[16];
    #pragma unroll
    for (int k = 0; k < 16; ++k) {
        const float* kp = K + ((long)b * R + ip[k]) * CC + h * 32;
        float d = 0.f;
        #pragma unroll
        for (int i = 0; i < 8; ++i) {
            f32x4 kv = *(const f32x4*)(kp + 4 * i);
            d += qv[i][0] * kv[0] + qv[i][1] * kv[1] + qv[i][2] * kv[2] + qv[i][3] * kv[3];
        }
        sc[k] = d * 0.17677669529663687f;
    }
    float mx = sc[0];
    #pragma unroll
    for (int k = 1; k < 16; ++k) mx = fmaxf(mx, sc[k]);
    float sum = 0.f;
    #pragma unroll
    for (int k = 0; k < 16; ++k) { sc[k] = __expf(sc[k] - mx); sum += sc[k]; }
    float inv = 1.0f / sum;
    float* op = wout + tid * 16;
    #pragma unroll
    for (int i = 0; i < 4; ++i) {
        f32x4 v = { sc[4*i] * inv, sc[4*i+1] * inv, sc[4*i+2] * inv, sc[4*i+3] * inv };
        *(f32x4*)(op + 4 * i) = v;
    }
}

// ---------------------------------------------------------------------------
// cvt: d0 (B,M,N) f32 -> d0b (B,M,N) bf16  +  d0t (B,N,M) bf16
// 64x64 tiles, grid (N/64, M/64, B)
// ---------------------------------------------------------------------------
__global__ __launch_bounds__(256) void cvt_kernel(
    const float* __restrict__ d0, unsigned short* __restrict__ d0b,
    unsigned short* __restrict__ d0t)
{
    __shared__ unsigned short T[64][66];   // [m-local][n-local]
    const int t = threadIdx.x;
    const int b = blockIdx.z;
    const long n0 = (long)blockIdx.x * 64;
    const long m0 = (long)blockIdx.y * 64;
    const int r = t >> 4, c4 = (t & 15) << 2;
    const float* src = d0 + ((long)b * MM + m0) * NN + n0;
    #pragma unroll
    for (int i = 0; i < 4; ++i) {
        int row = r + i * 16;
        f32x4 v = *(const f32x4*)(src + (long)row * NN + c4);
        *(uint2*)(d0b + ((long)b * MM + m0 + row) * NN + n0 + c4) =
            make_uint2(pk2(v[0], v[1]), pk2(v[2], v[3]));
        T[row][c4 + 0] = f2bf(v[0]);
        T[row][c4 + 1] = f2bf(v[1]);
        T[row][c4 + 2] = f2bf(v[2]);
        T[row][c4 + 3] = f2bf(v[3]);
    }
    __syncthreads();
    #pragma unroll
    for (int i = 0; i < 4; ++i) {
        int rn = r + i * 16;    // n-local
        unsigned lo = (unsigned)T[c4 + 0][rn] | ((unsigned)T[c4 + 1][rn] << 16);
        unsigned hi = (unsigned)T[c4 + 2][rn] | ((unsigned)T[c4 + 3][rn] << 16);
        *(uint2*)(d0t + ((long)b * NN + n0 + rn) * MM + m0 + c4) = make_uint2(lo, hi);
    }
}

// ---------------------------------------------------------------------------
// m97-style GEMM: out[s,b,row,c] = sum_{k in split s} A[b,row,k] * Bm[b,c,k]
// A: (B, RB, LD) bf16; Bm: (B, 256, LD) bf16; out: (NSPLIT, B, RB, 256) f32
// 128x128 tile, BK=64, global_load_lds staging, 4 waves x (64x64)
// grid (RB/128, 2, B*NSPLIT)
// ---------------------------------------------------------------------------
template<int RB, int NSPLIT, int LD>
__global__ __launch_bounds__(256) void gemm_kernel(
    const unsigned short* __restrict__ A, const unsigned short* __restrict__ Bm,
    float* __restrict__ out)
{
    constexpr int KS = LD / NSPLIT;
    __shared__ unsigned short Al[128 * 64];
    __shared__ unsigned short Bl[128 * 64];
    const int t = threadIdx.x;
    const int b = blockIdx.z / NSPLIT, s = blockIdx.z % NSPLIT;
    const long m0 = (long)blockIdx.x * 128;
    const int c0 = blockIdx.y * 128;
    const int w = t >> 6, lane = t & 63;
    const int q = lane >> 4, l15 = lane & 15;
    const int wr = (w >> 1) * 64, wc = (w & 1) * 64;
    const unsigned short* Ab = A + ((long)b * RB + m0) * LD + (long)s * KS;
    const unsigned short* Bb = Bm + ((long)b * CC + c0) * LD + (long)s * KS;
    const long laneOff = (long)(lane >> 3) * LD + (lane & 7) * 8;

    f32x4 acc[4][4];
    #pragma unroll
    for (int i = 0; i < 4; ++i)
        #pragma unroll
        for (int j = 0; j < 4; ++j) acc[i][j] = {0.f, 0.f, 0.f, 0.f};

    for (int k0 = 0; k0 < KS; k0 += 64) {
        #pragma unroll
        for (int j = 0; j < 4; ++j) {
            const int ch = w + 4 * j;
            gll16(Ab + (long)(ch * 8) * LD + k0 + laneOff, Al + ch * 512);
            gll16(Bb + (long)(ch * 8) * LD + k0 + laneOff, Bl + ch * 512);
        }
        __syncthreads();
        #pragma unroll
        for (int kh = 0; kh < 2; ++kh) {
            bf16x8 af[4], bfr[4];
            #pragma unroll
            for (int i = 0; i < 4; ++i)
                af[i] = *(const bf16x8*)(Al + (wr + i * 16 + l15) * 64 + kh * 32 + q * 8);
            #pragma unroll
            for (int j = 0; j < 4; ++j)
                bfr[j] = *(const bf16x8*)(Bl + (wc + j * 16 + l15) * 64 + kh * 32 + q * 8);
            #pragma unroll
            for (int i = 0; i < 4; ++i)
                #pragma unroll
                for (int j = 0; j < 4; ++j)
                    acc[i][j] = __builtin_amdgcn_mfma_f32_16x16x32_bf16(af[i], bfr[j], acc[i][j], 0, 0, 0);
        }
        __syncthreads();
    }

    float* ob = out + (((long)s * BB + b) * RB + m0) * CC + c0;
    #pragma unroll
    for (int i = 0; i < 4; ++i)
        #pragma unroll
        for (int j = 0; j < 4; ++j)
            #pragma unroll
            for (int r = 0; r < 4; ++r)
                ob[(long)(wr + i * 16 + q * 4 + r) * CC + wc + j * 16 + l15] = acc[i][j][r];
}

// ---------------------------------------------------------------------------
// gather_e: x2t[b,c,m] = bf16( sum_k ae[b,m,h(c),k] * (x1[0,b,idx,c]+x1[1,b,idx,c]) )
// ---------------------------------------------------------------------------
__global__ __launch_bounds__(256) void gather_e_kernel(
    const float* __restrict__ x1, const float* __restrict__ ae,
    const int* __restrict__ eidx, unsigned short* __restrict__ x2t)
{
    __shared__ unsigned short T[256][72];
    const int t = threadIdx.x;
    const int b = blockIdx.y;
    const int m0 = blockIdx.x * 64;
    const int h = t >> 5;
    const float* xa = x1 + (long)b * MM * CC;
    const float* xb = x1 + ((long)BB + b) * MM * CC;
    for (int ml = 0; ml < 64; ++ml) {
        int m = m0 + ml;
        const int* ip = eidx + (long)m * 16;
        const float* wp = ae + ((long)b * MM + m) * 128 + h * 16;
        float acc = 0.f;
        #pragma unroll
        for (int k = 0; k < 16; ++k) {
            long o = (long)ip[k] * CC + t;
            acc += wp[k] * (xa[o] + xb[o]);
        }
        T[t][ml] = f2bf(acc);
    }
    __syncthreads();
    unsigned short* dst = x2t + ((long)b * CC + t) * MM + m0;
    #pragma unroll
    for (int i = 0; i < 8; ++i)
        *(uint4*)(dst + i * 8) = *(const uint4*)(&T[t][i * 8]);
}

// ---------------------------------------------------------------------------
// gather_v: out[b,n,c] = sum_k av[b,n,h(c),k] * sum_{s=0..3} x3[s,b,vidx[n,k],c]
// ---------------------------------------------------------------------------
__global__ __launch_bounds__(256) void gather_v_kernel(
    const float* __restrict__ x3, const float* __restrict__ av,
    const int* __restrict__ vidx, float* __restrict__ out)
{
    const int t = threadIdx.x;
    const int b = blockIdx.y;
    const int n = blockIdx.x;
    const int h = t >> 5;
    const float* x0 = x3 + ((long)(0 * BB + b)) * NN * CC;
    const float* x1p = x3 + ((long)(1 * BB + b)) * NN * CC;
    const float* x2p = x3 + ((long)(2 * BB + b)) * NN * CC;
    const float* x3p = x3 + ((long)(3 * BB + b)) * NN * CC;
    const int* ip = vidx + (long)n * 16;
    const float* wp = av + ((long)b * NN + n) * 128 + h * 16;
    float acc = 0.f;
    #pragma unroll
    for (int k = 0; k < 16; ++k) {
        long j = (long)ip[k] * CC + t;
        acc += wp[k] * (x0[j] + x1p[j] + x2p[j] + x3p[j]);
    }
    out[((long)b * NN + n) * CC + t] = acc;
}

// ---------------------------------------------------------------------------
extern "C" void kernel_launch(void* const* d_in, const int* in_sizes, int n_in,
                              void* d_out, int out_size, void* d_ws, size_t ws_size,
                              hipStream_t stream)
{
    const float* x_v = (const float*)d_in[0];
    const float* x_e = (const float*)d_in[1];
    const float* d0  = (const float*)d_in[2];
    const float* WvQ = (const float*)d_in[3];
    const float* WvK = (const float*)d_in[4];
    const float* WvV = (const float*)d_in[5];
    const float* WeQ = (const float*)d_in[6];
    const float* WeK = (const float*)d_in[7];
    const int* vidx  = (const int*)d_in[8];
    const int* eidx  = (const int*)d_in[9];

    char* ws = (char*)d_ws;
    const size_t oVVt = 0;                        // 4,194,304  (B,C,N) bf16
    const size_t oAv  = oVVt + 4194304;           // 4,194,304
    const size_t oX2t = oAv  + 4194304;           // 12,582,912 (B,C,M) bf16
    const size_t oD0t = oX2t + 12582912;          // 201,326,592 (B,N,M) bf16
    const size_t oAe  = oD0t + 201326592;         // 12,582,912
    const size_t oVQ  = oAe  + 12582912;          // 8,388,608
    const size_t oVK  = oVQ  + 8388608;           // 8,388,608
    const size_t oR1  = oVK  + 8388608;           // 50,331,648: eQ+eK | x1(2 splits)
    const size_t oR2  = oR1  + 50331648;          // 201,326,592: d0b | x3(4 splits)
    const size_t total = oR2 + 201326592;         // 503,316,480
    if (total > ws_size) return;

    unsigned short* vVt = (unsigned short*)(ws + oVVt);
    float*          av  = (float*)(ws + oAv);
    unsigned short* x2t = (unsigned short*)(ws + oX2t);
    unsigned short* d0t = (unsigned short*)(ws + oD0t);
    float*          ae  = (float*)(ws + oAe);
    float*          vQ  = (float*)(ws + oVQ);
    float*          vK  = (float*)(ws + oVK);
    float*          eQ  = (float*)(ws + oR1);
    float*          eK  = (float*)(ws + oR1 + 25165824);
    float*          x1  = (float*)(ws + oR1);     // aliases eQ/eK (dead by then)
    unsigned short* d0b = (unsigned short*)(ws + oR2);
    float*          x3  = (float*)(ws + oR2);     // aliases d0b (dead by then)

    proj_kernel<<<dim3((BB * NN) / 64), 256, 0, stream>>>(x_v, WvQ, vQ, nullptr, NN, 0);
    proj_kernel<<<dim3((BB * NN) / 64), 256, 0, stream>>>(x_v, WvK, vK, nullptr, NN, 0);
    proj_kernel<<<dim3((BB * NN) / 64), 256, 0, stream>>>(x_v, WvV, nullptr, vVt, NN, 1);
    proj_kernel<<<dim3((BB * MM) / 64), 256, 0, stream>>>(x_e, WeQ, eQ, nullptr, MM, 0);
    proj_kernel<<<dim3((BB * MM) / 64), 256, 0, stream>>>(x_e, WeK, eK, nullptr, MM, 0);
    attnw_kernel<<<dim3((BB * MM * HH) / 256), 256, 0, stream>>>(eQ, eK, eidx, ae, MM);
    // second sparse attention uses q = v_K, k = v_Q (swap in the reference)
    attnw_kernel<<<dim3((BB * NN * HH) / 256), 256, 0, stream>>>(vK, vQ, vidx, av, NN);
    cvt_kernel<<<dim3(NN / 64, MM / 64, BB), 256, 0, stream>>>(d0, d0b, d0t);
    gemm_kernel<MM, 2, NN><<<dim3(MM / 128, 2, BB * 2), 256, 0, stream>>>(d0b, vVt, x1);
    gather_e_kernel<<<dim3(MM / 64, BB), 256, 0, stream>>>(x1, ae, eidx, x2t);
    gemm_kernel<NN, 4, MM><<<dim3(NN / 128, 2, BB * 4), 256, 0, stream>>>(d0t, x2t, x3);
    gather_v_kernel<<<dim3(NN, BB), 256, 0, stream>>>(x3, av, vidx, (float*)d_out);
}

// Round 3
// 1003.185 us; speedup vs baseline: 1.3153x; 1.2400x over previous
//
#include <hip/hip_runtime.h>

#define BB 2
#define NN 4096
#define MM 12288
#define HH 8
#define CC 256

typedef float f32x4 __attribute__((ext_vector_type(4)));
typedef __bf16 bf16x8 __attribute__((ext_vector_type(8)));

__device__ __forceinline__ unsigned short f2bf(float f) {
    union { float f; unsigned u; } v; v.f = f;
    unsigned r = (v.u + 0x7FFFu + ((v.u >> 16) & 1u)) >> 16;
    return (unsigned short)r;
}
__device__ __forceinline__ float bf2f(unsigned short u) {
    union { unsigned u; float f; } v; v.u = ((unsigned)u) << 16; return v.f;
}
__device__ __forceinline__ unsigned pk2(float a, float b) {
    return (unsigned)f2bf(a) | ((unsigned)f2bf(b) << 16);
}
__device__ __forceinline__ void gll16(const unsigned short* g, unsigned short* l) {
    __builtin_amdgcn_global_load_lds(
        (__attribute__((address_space(1))) void*)(g),
        (__attribute__((address_space(3))) void*)(l), 16, 0, 0);
}

// ---------------------------------------------------------------------------
// proj: out[r,e] = sum_d X[r,d] * W[e,d] for NW weight matrices, X staged once.
// widx 0 -> outQ (f32, per-head LN), widx 1 -> outK (f32, per-head LN),
// widx 2 (NW=3) -> outT bf16 transposed: outT[(b*256+c)*Nb + n]
// grid (R/64, 2): y splits the 8 col-chunks into 4+4. W chunks prefetched.
// ---------------------------------------------------------------------------
template<int NW>
__global__ __launch_bounds__(256) void proj_kernel(
    const float* __restrict__ X, const float* __restrict__ W0,
    const float* __restrict__ W1, const float* __restrict__ W2,
    float* __restrict__ outQ, float* __restrict__ outK,
    unsigned short* __restrict__ outT, int Nb)
{
    __shared__ unsigned short Al[64][264];
    __shared__ unsigned short Wl[32][264];
    const int t = threadIdx.x;
    const long rowbase = (long)blockIdx.x * 64;
    const int cty = blockIdx.y;
    const int lane = t & 63, w = t >> 6, q = lane >> 4, l15 = lane & 15;

    {   // stage X rows once (f32 -> bf16)
        const float* Xp = X + rowbase * CC;
        #pragma unroll
        for (int i = 0; i < 16; ++i) {
            int f = t + i * 256;
            int row = f >> 6, k4 = (f & 63) << 2;
            f32x4 v = *(const f32x4*)(Xp + row * CC + k4);
            *(uint2*)(&Al[row][k4]) = make_uint2(pk2(v[0], v[1]), pk2(v[2], v[3]));
        }
    }

    f32x4 pf[8];
    auto loadchunk = [&](int g) {
        const float* Wp = (g >> 2) == 0 ? W0 : ((g >> 2) == 1 ? W1 : W2);
        int rb = (cty * 4 + (g & 3)) * 32;
        #pragma unroll
        for (int i = 0; i < 8; ++i) {
            int f = t + i * 256;
            int row = f >> 6, k4 = (f & 63) << 2;
            pf[i] = *(const f32x4*)(Wp + (rb + row) * CC + k4);
        }
    };
    loadchunk(0);

    const int wrow = w * 16;
    for (int g = 0; g < NW * 4; ++g) {
        const int widx = g >> 2;
        const int ct = cty * 4 + (g & 3);
        #pragma unroll
        for (int i = 0; i < 8; ++i) {
            int f = t + i * 256;
            int row = f >> 6, k4 = (f & 63) << 2;
            *(uint2*)(&Wl[row][k4]) = make_uint2(pk2(pf[i][0], pf[i][1]), pk2(pf[i][2], pf[i][3]));
        }
        __syncthreads();
        if (g + 1 < NW * 4) loadchunk(g + 1);
        f32x4 acc0 = {0.f, 0.f, 0.f, 0.f}, acc1 = {0.f, 0.f, 0.f, 0.f};
        #pragma unroll
        for (int kk = 0; kk < 8; ++kk) {
            bf16x8 af = *(const bf16x8*)(&Al[wrow + l15][kk * 32 + q * 8]);
            bf16x8 b0 = *(const bf16x8*)(&Wl[l15][kk * 32 + q * 8]);
            bf16x8 b1 = *(const bf16x8*)(&Wl[16 + l15][kk * 32 + q * 8]);
            acc0 = __builtin_amdgcn_mfma_f32_16x16x32_bf16(af, b0, acc0, 0, 0, 0);
            acc1 = __builtin_amdgcn_mfma_f32_16x16x32_bf16(af, b1, acc1, 0, 0, 0);
        }
        if (widx < 2 || NW == 2) {
            float* outF = (widx == 0) ? outQ : outK;
            #pragma unroll
            for (int r = 0; r < 4; ++r) {
                float s = acc0[r] + acc1[r];
                s += __shfl_xor(s, 1); s += __shfl_xor(s, 2);
                s += __shfl_xor(s, 4); s += __shfl_xor(s, 8);
                float mu = s * (1.0f / 32.0f);
                float a0 = acc0[r] - mu, a1 = acc1[r] - mu;
                float sq = a0 * a0 + a1 * a1;
                sq += __shfl_xor(sq, 1); sq += __shfl_xor(sq, 2);
                sq += __shfl_xor(sq, 4); sq += __shfl_xor(sq, 8);
                float rs = rsqrtf(sq * (1.0f / 32.0f) + 1e-5f);
                long row = rowbase + wrow + q * 4 + r;
                outF[row * CC + ct * 32 + l15] = a0 * rs;
                outF[row * CC + ct * 32 + 16 + l15] = a1 * rs;
            }
        } else {
            long row = rowbase + wrow + q * 4;
            int b = (row >= Nb) ? 1 : 0;
            long n = row - (long)b * Nb;
            int c0 = ct * 32 + l15;
            unsigned short* p0 = outT + ((long)(b * CC + c0)) * Nb + n;
            *(uint2*)p0 = make_uint2(pk2(acc0[0], acc0[1]), pk2(acc0[2], acc0[3]));
            unsigned short* p1 = outT + ((long)(b * CC + c0 + 16)) * Nb + n;
            *(uint2*)p1 = make_uint2(pk2(acc1[0], acc1[1]), pk2(acc1[2], acc1[3]));
        }
        __syncthreads();
    }
}

// ---------------------------------------------------------------------------
// attention weights: one thread per (b, r, h)
// ---------------------------------------------------------------------------
__global__ __launch_bounds__(256) void attnw_kernel(
    const float* __restrict__ Q, const float* __restrict__ K,
    const int* __restrict__ idx, float* __restrict__ wout, int R)
{
    long tid = (long)blockIdx.x * 256 + threadIdx.x;
    int h = (int)(tid & 7);
    long br = tid >> 3;
    int b = (br >= R) ? 1 : 0;
    long r = br - (long)b * R;
    const float* qp = Q + br * CC + h * 32;
    f32x4 qv[8];
    #pragma unroll
    for (int i = 0; i < 8; ++i) qv[i] = *(const f32x4*)(qp + 4 * i);
    const int* ip = idx + r * 16;
    float sc[16];
    #pragma unroll
    for (int k = 0; k < 16; ++k) {
        const float* kp = K + ((long)b * R + ip[k]) * CC + h * 32;
        float d = 0.f;
        #pragma unroll
        for (int i = 0; i < 8; ++i) {
            f32x4 kv = *(const f32x4*)(kp + 4 * i);
            d += qv[i][0] * kv[0] + qv[i][1] * kv[1] + qv[i][2] * kv[2] + qv[i][3] * kv[3];
        }
        sc[k] = d * 0.17677669529663687f;
    }
    float mx = sc[0];
    #pragma unroll
    for (int k = 1; k < 16; ++k) mx = fmaxf(mx, sc[k]);
    float sum = 0.f;
    #pragma unroll
    for (int k = 0; k < 16; ++k) { sc[k] = __expf(sc[k] - mx); sum += sc[k]; }
    float inv = 1.0f / sum;
    float* op = wout + tid * 16;
    #pragma unroll
    for (int i = 0; i < 4; ++i) {
        f32x4 v = { sc[4*i] * inv, sc[4*i+1] * inv, sc[4*i+2] * inv, sc[4*i+3] * inv };
        *(f32x4*)(op + 4 * i) = v;
    }
}

// ---------------------------------------------------------------------------
// cvt: d0 (B,M,N) f32 -> d0b (B,M,N) bf16  +  d0t (B,N,M) bf16
// ---------------------------------------------------------------------------
__global__ __launch_bounds__(256) void cvt_kernel(
    const float* __restrict__ d0, unsigned short* __restrict__ d0b,
    unsigned short* __restrict__ d0t)
{
    __shared__ unsigned short T[64][66];
    const int t = threadIdx.x;
    const int b = blockIdx.z;
    const long n0 = (long)blockIdx.x * 64;
    const long m0 = (long)blockIdx.y * 64;
    const int r = t >> 4, c4 = (t & 15) << 2;
    const float* src = d0 + ((long)b * MM + m0) * NN + n0;
    #pragma unroll
    for (int i = 0; i < 4; ++i) {
        int row = r + i * 16;
        f32x4 v = *(const f32x4*)(src + (long)row * NN + c4);
        *(uint2*)(d0b + ((long)b * MM + m0 + row) * NN + n0 + c4) =
            make_uint2(pk2(v[0], v[1]), pk2(v[2], v[3]));
        T[row][c4 + 0] = f2bf(v[0]);
        T[row][c4 + 1] = f2bf(v[1]);
        T[row][c4 + 2] = f2bf(v[2]);
        T[row][c4 + 3] = f2bf(v[3]);
    }
    __syncthreads();
    #pragma unroll
    for (int i = 0; i < 4; ++i) {
        int rn = r + i * 16;
        unsigned lo = (unsigned)T[c4 + 0][rn] | ((unsigned)T[c4 + 1][rn] << 16);
        unsigned hi = (unsigned)T[c4 + 2][rn] | ((unsigned)T[c4 + 3][rn] << 16);
        *(uint2*)(d0t + ((long)b * NN + n0 + rn) * MM + m0 + c4) = make_uint2(lo, hi);
    }
}

// ---------------------------------------------------------------------------
// m97-style GEMM: out[s,b,row,c] = bf16( sum_{k in split s} A[b,row,k]*Bm[b,c,k] )
// 128x128 tile, BK=64, global_load_lds, 4 waves x (64x64). grid (RB/128, 2, B*NSPLIT)
// ---------------------------------------------------------------------------
template<int RB, int NSPLIT, int LD>
__global__ __launch_bounds__(256) void gemm_kernel(
    const unsigned short* __restrict__ A, const unsigned short* __restrict__ Bm,
    unsigned short* __restrict__ out)
{
    constexpr int KS = LD / NSPLIT;
    __shared__ unsigned short Al[128 * 64];
    __shared__ unsigned short Bl[128 * 64];
    const int t = threadIdx.x;
    const int b = blockIdx.z / NSPLIT, s = blockIdx.z % NSPLIT;
    const long m0 = (long)blockIdx.x * 128;
    const int c0 = blockIdx.y * 128;
    const int w = t >> 6, lane = t & 63;
    const int q = lane >> 4, l15 = lane & 15;
    const int wr = (w >> 1) * 64, wc = (w & 1) * 64;
    const unsigned short* Ab = A + ((long)b * RB + m0) * LD + (long)s * KS;
    const unsigned short* Bb = Bm + ((long)b * CC + c0) * LD + (long)s * KS;
    const long laneOff = (long)(lane >> 3) * LD + (lane & 7) * 8;

    f32x4 acc[4][4];
    #pragma unroll
    for (int i = 0; i < 4; ++i)
        #pragma unroll
        for (int j = 0; j < 4; ++j) acc[i][j] = {0.f, 0.f, 0.f, 0.f};

    for (int k0 = 0; k0 < KS; k0 += 64) {
        #pragma unroll
        for (int j = 0; j < 4; ++j) {
            const int ch = w + 4 * j;
            gll16(Ab + (long)(ch * 8) * LD + k0 + laneOff, Al + ch * 512);
            gll16(Bb + (long)(ch * 8) * LD + k0 + laneOff, Bl + ch * 512);
        }
        __syncthreads();
        #pragma unroll
        for (int kh = 0; kh < 2; ++kh) {
            bf16x8 af[4], bfr[4];
            #pragma unroll
            for (int i = 0; i < 4; ++i)
                af[i] = *(const bf16x8*)(Al + (wr + i * 16 + l15) * 64 + kh * 32 + q * 8);
            #pragma unroll
            for (int j = 0; j < 4; ++j)
                bfr[j] = *(const bf16x8*)(Bl + (wc + j * 16 + l15) * 64 + kh * 32 + q * 8);
            #pragma unroll
            for (int i = 0; i < 4; ++i)
                #pragma unroll
                for (int j = 0; j < 4; ++j)
                    acc[i][j] = __builtin_amdgcn_mfma_f32_16x16x32_bf16(af[i], bfr[j], acc[i][j], 0, 0, 0);
        }
        __syncthreads();
    }

    unsigned short* ob = out + (((long)s * BB + b) * RB + m0) * CC + c0;
    #pragma unroll
    for (int i = 0; i < 4; ++i)
        #pragma unroll
        for (int j = 0; j < 4; ++j)
            #pragma unroll
            for (int r = 0; r < 4; ++r)
                ob[(long)(wr + i * 16 + q * 4 + r) * CC + wc + j * 16 + l15] = f2bf(acc[i][j][r]);
}

// ---------------------------------------------------------------------------
// gather_e: x2t[b,c,m] = bf16( sum_k ae[b,m,h(c),k] * (x1[0,..]+x1[1,..]) )
// grid (M/64, B, 2): z = c-half. waves 0/1: even ml, waves 2/3: odd ml.
// ---------------------------------------------------------------------------
__global__ __launch_bounds__(256) void gather_e_kernel(
    const unsigned short* __restrict__ x1, const float* __restrict__ ae,
    const int* __restrict__ eidx, unsigned short* __restrict__ x2t)
{
    __shared__ unsigned short T[128][66];
    const int t = threadIdx.x;
    const int b = blockIdx.y;
    const int m0 = blockIdx.x * 64;
    const int ch = blockIdx.z;
    const int cl = t & 127;
    const int c = ch * 128 + cl;
    const int mlh = t >> 7;
    const int h = c >> 5;
    const unsigned short* xa = x1 + (long)b * MM * CC;
    const unsigned short* xb = x1 + ((long)BB + b) * MM * CC;
    for (int mi = 0; mi < 32; ++mi) {
        int ml = mi * 2 + mlh;
        int m = m0 + ml;
        const int* ip = eidx + (long)m * 16;
        const float* wp = ae + ((long)b * MM + m) * 128 + h * 16;
        float acc = 0.f;
        #pragma unroll
        for (int k = 0; k < 16; ++k) {
            long o = (long)ip[k] * CC + c;
            acc += wp[k] * (bf2f(xa[o]) + bf2f(xb[o]));
        }
        T[cl][ml] = f2bf(acc);
    }
    __syncthreads();
    #pragma unroll
    for (int i = 0; i < 4; ++i) {
        int flat = t + i * 256;
        int rcl = flat >> 3, u4 = flat & 7;
        unsigned short* dst = x2t + ((long)b * CC + ch * 128 + rcl) * MM + m0 + u4 * 8;
        *(uint4*)dst = *(const uint4*)(&T[rcl][u4 * 8]);
    }
}

// ---------------------------------------------------------------------------
// gather_v: out[b,n,c] = sum_k av[b,n,h(c),k] * sum_{s=0..3} x3[s,b,vidx[n,k],c]
// ---------------------------------------------------------------------------
__global__ __launch_bounds__(256) void gather_v_kernel(
    const unsigned short* __restrict__ x3, const float* __restrict__ av,
    const int* __restrict__ vidx, float* __restrict__ out)
{
    const int t = threadIdx.x;
    const int b = blockIdx.y;
    const int n = blockIdx.x;
    const int h = t >> 5;
    const unsigned short* x0 = x3 + ((long)(0 * BB + b)) * NN * CC;
    const unsigned short* x1p = x3 + ((long)(1 * BB + b)) * NN * CC;
    const unsigned short* x2p = x3 + ((long)(2 * BB + b)) * NN * CC;
    const unsigned short* x3p = x3 + ((long)(3 * BB + b)) * NN * CC;
    const int* ip = vidx + (long)n * 16;
    const float* wp = av + ((long)b * NN + n) * 128 + h * 16;
    float acc = 0.f;
    #pragma unroll
    for (int k = 0; k < 16; ++k) {
        long j = (long)ip[k] * CC + t;
        acc += wp[k] * (bf2f(x0[j]) + bf2f(x1p[j]) + bf2f(x2p[j]) + bf2f(x3p[j]));
    }
    out[((long)b * NN + n) * CC + t] = acc;
}

// ---------------------------------------------------------------------------
extern "C" void kernel_launch(void* const* d_in, const int* in_sizes, int n_in,
                              void* d_out, int out_size, void* d_ws, size_t ws_size,
                              hipStream_t stream)
{
    const float* x_v = (const float*)d_in[0];
    const float* x_e = (const float*)d_in[1];
    const float* d0  = (const float*)d_in[2];
    const float* WvQ = (const float*)d_in[3];
    const float* WvK = (const float*)d_in[4];
    const float* WvV = (const float*)d_in[5];
    const float* WeQ = (const float*)d_in[6];
    const float* WeK = (const float*)d_in[7];
    const int* vidx  = (const int*)d_in[8];
    const int* eidx  = (const int*)d_in[9];

    char* ws = (char*)d_ws;
    const size_t oVVt = 0;                        // 4,194,304
    const size_t oAv  = oVVt + 4194304;           // 4,194,304
    const size_t oX2t = oAv  + 4194304;           // 12,582,912
    const size_t oD0t = oX2t + 12582912;          // 201,326,592
    const size_t oAe  = oD0t + 201326592;         // 12,582,912
    const size_t oVQ  = oAe  + 12582912;          // 8,388,608
    const size_t oVK  = oVQ  + 8388608;           // 8,388,608
    const size_t oEQ  = oVK  + 8388608;           // 25,165,824 (x1 bf16 aliases, dead by then)
    const size_t oEK  = oEQ  + 25165824;          // 25,165,824 (x3 bf16 aliases, dead by then)
    const size_t oD0b = oEK  + 25165824;          // 201,326,592
    const size_t total = oD0b + 201326592;        // 503,316,480
    if (total > ws_size) return;

    unsigned short* vVt = (unsigned short*)(ws + oVVt);
    float*          av  = (float*)(ws + oAv);
    unsigned short* x2t = (unsigned short*)(ws + oX2t);
    unsigned short* d0t = (unsigned short*)(ws + oD0t);
    float*          ae  = (float*)(ws + oAe);
    float*          vQ  = (float*)(ws + oVQ);
    float*          vK  = (float*)(ws + oVK);
    float*          eQ  = (float*)(ws + oEQ);
    float*          eK  = (float*)(ws + oEK);
    unsigned short* x1  = (unsigned short*)(ws + oEQ);   // alias eQ (dead)
    unsigned short* x3  = (unsigned short*)(ws + oEK);   // alias eK (dead)
    unsigned short* d0b = (unsigned short*)(ws + oD0b);

    proj_kernel<3><<<dim3((BB * NN) / 64, 2), 256, 0, stream>>>(x_v, WvQ, WvK, WvV, vQ, vK, vVt, NN);
    proj_kernel<2><<<dim3((BB * MM) / 64, 2), 256, 0, stream>>>(x_e, WeQ, WeK, nullptr, eQ, eK, nullptr, MM);
    attnw_kernel<<<dim3((BB * MM * HH) / 256), 256, 0, stream>>>(eQ, eK, eidx, ae, MM);
    // second sparse attention uses q = v_K, k = v_Q (swap in the reference)
    attnw_kernel<<<dim3((BB * NN * HH) / 256), 256, 0, stream>>>(vK, vQ, vidx, av, NN);
    cvt_kernel<<<dim3(NN / 64, MM / 64, BB), 256, 0, stream>>>(d0, d0b, d0t);
    gemm_kernel<MM, 2, NN><<<dim3(MM / 128, 2, BB * 2), 256, 0, stream>>>(d0b, vVt, x1);
    gather_e_kernel<<<dim3(MM / 64, BB, 2), 256, 0, stream>>>(x1, ae, eidx, x2t);
    gemm_kernel<NN, 4, MM><<<dim3(NN / 128, 2, BB * 4), 256, 0, stream>>>(d0t, x2t, x3);
    gather_v_kernel<<<dim3(NN, BB), 256, 0, stream>>>(x3, av, vidx, (float*)d_out);
}